// Round 1
// baseline (259.751 us; speedup 1.0000x reference)
//
#include <hip/hip_runtime.h>
#include <math.h>

#define Bsz 512
#define INsz 128
#define Nn 256
#define Ww 64
#define Rr 4
#define Uu 256
#define OUTsz 128
#define IFACEsz 471
#define XDIM 384   /* IN + W*R */
#define KL 640     /* XDIM + U */
#define G4 1024    /* 4*U */

__device__ __forceinline__ float sigf(float x){ return 1.0f/(1.0f+expf(-x)); }
__device__ __forceinline__ float softplusf_(float x){ return fmaxf(x,0.0f) + log1pf(expf(-fabsf(x))); }

// ---------------- K1: LSTM controller -------------------------------------
// grid = B/4 blocks, 256 threads. Thread t computes cols 4t..4t+3 of z for 4 batches.
__global__ __launch_bounds__(256) void k_lstm(
  const float* __restrict__ inputs, const float* __restrict__ rvp,
  const float* __restrict__ hp, const float* __restrict__ cprev,
  const float* __restrict__ Wk, const float* __restrict__ Wr,
  const float* __restrict__ bl, float* __restrict__ h_out)
{
  __shared__ float xl[4][KL];
  __shared__ float zl[4][G4];
  const int t = threadIdx.x;
  const int b0 = blockIdx.x*4;
  for (int idx=t; idx<4*KL; idx+=256){
    int bb = idx/KL, k = idx - bb*KL;
    int b = b0+bb;
    float v;
    if (k < INsz)      v = inputs[b*INsz + k];
    else if (k < XDIM) v = rvp[b*(Ww*Rr) + (k-INsz)];
    else               v = hp[b*Uu + (k-XDIM)];
    xl[bb][k] = v;
  }
  __syncthreads();
  float4 bias4 = *reinterpret_cast<const float4*>(bl + 4*t);
  float4 a0 = bias4, a1 = bias4, a2 = bias4, a3 = bias4;
  #pragma unroll 4
  for (int k=0;k<XDIM;++k){
    float4 w = *reinterpret_cast<const float4*>(Wk + (size_t)k*G4 + 4*t);
    float x0=xl[0][k], x1=xl[1][k], x2=xl[2][k], x3=xl[3][k];
    a0.x+=x0*w.x; a0.y+=x0*w.y; a0.z+=x0*w.z; a0.w+=x0*w.w;
    a1.x+=x1*w.x; a1.y+=x1*w.y; a1.z+=x1*w.z; a1.w+=x1*w.w;
    a2.x+=x2*w.x; a2.y+=x2*w.y; a2.z+=x2*w.z; a2.w+=x2*w.w;
    a3.x+=x3*w.x; a3.y+=x3*w.y; a3.z+=x3*w.z; a3.w+=x3*w.w;
  }
  #pragma unroll 4
  for (int k=0;k<Uu;++k){
    float4 w = *reinterpret_cast<const float4*>(Wr + (size_t)k*G4 + 4*t);
    float x0=xl[0][XDIM+k], x1=xl[1][XDIM+k], x2=xl[2][XDIM+k], x3=xl[3][XDIM+k];
    a0.x+=x0*w.x; a0.y+=x0*w.y; a0.z+=x0*w.z; a0.w+=x0*w.w;
    a1.x+=x1*w.x; a1.y+=x1*w.y; a1.z+=x1*w.z; a1.w+=x1*w.w;
    a2.x+=x2*w.x; a2.y+=x2*w.y; a2.z+=x2*w.z; a2.w+=x2*w.w;
    a3.x+=x3*w.x; a3.y+=x3*w.y; a3.z+=x3*w.z; a3.w+=x3*w.w;
  }
  *reinterpret_cast<float4*>(&zl[0][4*t]) = a0;
  *reinterpret_cast<float4*>(&zl[1][4*t]) = a1;
  *reinterpret_cast<float4*>(&zl[2][4*t]) = a2;
  *reinterpret_cast<float4*>(&zl[3][4*t]) = a3;
  __syncthreads();
  #pragma unroll
  for (int bb=0;bb<4;++bb){
    int b = b0+bb;
    float zi = zl[bb][t], zf = zl[bb][t+Uu], zc = zl[bb][t+2*Uu], zo = zl[bb][t+3*Uu];
    float c = sigf(zf)*cprev[b*Uu+t] + sigf(zi)*tanhf(zc);
    float h = sigf(zo)*tanhf(c);
    h = fminf(fmaxf(h,-20.0f),20.0f);
    h_out[b*Uu+t] = h;
  }
}

// ---------------- K2: interface + usage/alloc + write addressing ----------
// grid = B blocks, 256 threads (= one thread per memory slot n).
__global__ __launch_bounds__(256) void k_iface(
  const float* __restrict__ h_ws, const float* __restrict__ Wi, const float* __restrict__ bi,
  const float* __restrict__ usage, const float* __restrict__ wwp,
  const float* __restrict__ wrp, const float* __restrict__ prec,
  const float* __restrict__ M,
  float* __restrict__ ww_ws, float* __restrict__ er_ws, float* __restrict__ wv_ws,
  float* __restrict__ rk_ws, float* __restrict__ krn_ws, float* __restrict__ rstr_ws,
  float* __restrict__ rm_ws, float* __restrict__ P_ws, float* __restrict__ Q_ws)
{
  const int b = blockIdx.x, t = threadIdx.x;
  __shared__ float hl[Uu];
  __shared__ float vl[IFACEsz];
  __shared__ float wkey[Ww];
  __shared__ float ul[Nn], sul[Nn], cpl[Nn], red[Nn];
  __shared__ float scal[8]; // 0 wstr, 1 agate, 2 wgate, 3 kwn, 4..7 free gates
  hl[t] = h_ws[b*Uu + t];
  __syncthreads();
  for (int j=t; j<IFACEsz; j+=256){
    float acc = bi[j];
    #pragma unroll 4
    for (int k=0;k<Uu;++k) acc += hl[k]*Wi[(size_t)k*IFACEsz + j];
    vl[j] = acc;
  }
  __syncthreads();
  if (t < Ww){
    wkey[t] = vl[260+t];
    er_ws[b*Ww+t] = sigf(vl[325+t]);
    wv_ws[b*Ww+t] = vl[389+t];
  }
  rk_ws[b*Ww*Rr + t] = vl[t];   // read_keys flat [w*R+r], t < 256
  if (t < Rr){
    rstr_ws[b*Rr+t] = 1.0f + softplusf_(vl[256+t]);
    float ssum = 0.0f;
    for (int w=0;w<Ww;++w){ float v = vl[w*Rr+t]; ssum += v*v; }
    krn_ws[b*Rr+t] = sqrtf(ssum);
    float q0=vl[459+t], q1=vl[463+t], q2=vl[467+t];
    float mm = fmaxf(q0, fmaxf(q1,q2));
    float e0=expf(q0-mm), e1=expf(q1-mm), e2=expf(q2-mm);
    float inv = 1.0f/(e0+e1+e2);
    rm_ws[b*12 + t]     = e0*inv;
    rm_ws[b*12 + 4 + t] = e1*inv;
    rm_ws[b*12 + 8 + t] = e2*inv;
    scal[4+t] = sigf(vl[453+t]);
  }
  if (t == 0){
    scal[0] = 1.0f + softplusf_(vl[324]);
    scal[1] = sigf(vl[457]);
    scal[2] = sigf(vl[458]);
    float ssum=0.0f;
    for (int w=0;w<Ww;++w){ float v=vl[260+w]; ssum += v*v; }
    scal[3] = sqrtf(ssum);
  }
  __syncthreads();
  // psi, u
  float4 wr4 = *reinterpret_cast<const float4*>(wrp + ((size_t)b*Nn + t)*Rr);
  float psi = (1.0f - scal[4]*wr4.x)*(1.0f - scal[5]*wr4.y)
            * (1.0f - scal[6]*wr4.z)*(1.0f - scal[7]*wr4.w);
  float us = usage[b*Nn+t], wp = wwp[b*Nn+t];
  float u = (us + wp - us*wp)*psi;
  ul[t] = u;
  __syncthreads();
  // stable-ascending rank (== argsort position)
  int rank = 0;
  for (int m=0;m<Nn;++m){
    float um = ul[m];
    rank += (um < u || (um == u && m < t)) ? 1 : 0;
  }
  sul[rank] = u;
  __syncthreads();
  // inclusive cumprod scan (Hillis-Steele)
  cpl[t] = sul[t];
  __syncthreads();
  for (int d=1; d<Nn; d<<=1){
    float a = cpl[t];
    float m_ = (t >= d) ? cpl[t-d] : 1.0f;
    __syncthreads();
    cpl[t] = a*m_;
    __syncthreads();
  }
  float cpexcl = (rank == 0) ? 1.0f : cpl[rank-1];
  float alloc = (1.0f - u)*cpexcl;
  // write content addressing (cosine)
  const float* Mrow = M + ((size_t)b*Nn + t)*Ww;
  float dot=0.0f, nrm=0.0f;
  #pragma unroll 4
  for (int w=0;w<Ww;w+=4){
    float4 m4 = *reinterpret_cast<const float4*>(Mrow + w);
    dot += m4.x*wkey[w] + m4.y*wkey[w+1] + m4.z*wkey[w+2] + m4.w*wkey[w+3];
    nrm += m4.x*m4.x + m4.y*m4.y + m4.z*m4.z + m4.w*m4.w;
  }
  float sim = dot/(sqrtf(nrm)*scal[3] + 1e-6f);
  float sc = scal[0]*sim;
  red[t] = sc; __syncthreads();
  for (int st=128; st>0; st>>=1){ if (t<st) red[t] = fmaxf(red[t], red[t+st]); __syncthreads(); }
  float mx = red[0]; __syncthreads();
  float e = expf(sc - mx);
  red[t] = e; __syncthreads();
  for (int st=128; st>0; st>>=1){ if (t<st) red[t] += red[t+st]; __syncthreads(); }
  float cw = e/red[0];
  float ww = scal[2]*(scal[1]*alloc + (1.0f - scal[1])*cw);
  ww_ws[b*Nn+t] = ww;
  __syncthreads();
  // P[r] = sum prec*wrp ; Q[r] = sum ww*wrp
  float pr = prec[b*Nn+t];
  float wrv[4] = {wr4.x, wr4.y, wr4.z, wr4.w};
  #pragma unroll
  for (int r=0;r<Rr;++r){
    red[t] = pr*wrv[r]; __syncthreads();
    for (int st=128; st>0; st>>=1){ if (t<st) red[t]+=red[t+st]; __syncthreads(); }
    if (t==0) P_ws[b*Rr+r] = red[0];
    __syncthreads();
    red[t] = ww*wrv[r]; __syncthreads();
    for (int st=128; st>0; st>>=1){ if (t<st) red[t]+=red[t+st]; __syncthreads(); }
    if (t==0) Q_ws[b*Rr+r] = red[0];
    __syncthreads();
  }
}

// ---------------- K3: link row/col products --------------------------------
// grid = B blocks, 256 threads. Two passes over link (col pass, row pass).
__global__ __launch_bounds__(256) void k_link(
  const float* __restrict__ link, const float* __restrict__ wrp,
  const float* __restrict__ ww_ws,
  float* __restrict__ rowA, float* __restrict__ rowC,
  float* __restrict__ colA, float* __restrict__ colC, float* __restrict__ diag)
{
  const int b = blockIdx.x, t = threadIdx.x;
  __shared__ float4 wrl4[Nn];
  __shared__ float wwl[Nn];
  wrl4[t] = *reinterpret_cast<const float4*>(wrp + ((size_t)b*Nn + t)*Rr);
  wwl[t]  = ww_ws[b*Nn + t];
  __syncthreads();
  const float* Lb = link + (size_t)b*Nn*Nn;
  // col pass: thread = column m
  float cA0=0,cA1=0,cA2=0,cA3=0,cC0=0,cC1=0,cC2=0,cC3=0, dg=0;
  #pragma unroll 4
  for (int n=0;n<Nn;++n){
    float l = Lb[(size_t)n*Nn + t];
    float4 w = wrl4[n];
    float lw = l*wwl[n];
    cA0 += l*w.x;  cA1 += l*w.y;  cA2 += l*w.z;  cA3 += l*w.w;
    cC0 += lw*w.x; cC1 += lw*w.y; cC2 += lw*w.z; cC3 += lw*w.w;
    if (n==t) dg = l;
  }
  {
    size_t o = ((size_t)b*Nn + t)*Rr;
    colA[o+0]=cA0; colA[o+1]=cA1; colA[o+2]=cA2; colA[o+3]=cA3;
    colC[o+0]=cC0; colC[o+1]=cC1; colC[o+2]=cC2; colC[o+3]=cC3;
    diag[b*Nn+t]=dg;
  }
  // row pass: 16 lanes per row, 4 rows per wave concurrently
  const int lane = t & 63, wave = t >> 6;
  const int g = lane >> 4, li = lane & 15;
  for (int it=0; it<16; ++it){
    int n = wave*64 + it*4 + g;
    const float* Lr = Lb + (size_t)n*Nn;
    float rA0=0,rA1=0,rA2=0,rA3=0,rC0=0,rC1=0,rC2=0,rC3=0;
    #pragma unroll
    for (int j=0;j<4;++j){
      int m0 = li*4 + j*64;
      float4 l4 = *reinterpret_cast<const float4*>(Lr + m0);
      float4 w; float lw;
      w = wrl4[m0+0]; lw = l4.x*wwl[m0+0];
      rA0+=l4.x*w.x; rA1+=l4.x*w.y; rA2+=l4.x*w.z; rA3+=l4.x*w.w;
      rC0+=lw*w.x;   rC1+=lw*w.y;   rC2+=lw*w.z;   rC3+=lw*w.w;
      w = wrl4[m0+1]; lw = l4.y*wwl[m0+1];
      rA0+=l4.y*w.x; rA1+=l4.y*w.y; rA2+=l4.y*w.z; rA3+=l4.y*w.w;
      rC0+=lw*w.x;   rC1+=lw*w.y;   rC2+=lw*w.z;   rC3+=lw*w.w;
      w = wrl4[m0+2]; lw = l4.z*wwl[m0+2];
      rA0+=l4.z*w.x; rA1+=l4.z*w.y; rA2+=l4.z*w.z; rA3+=l4.z*w.w;
      rC0+=lw*w.x;   rC1+=lw*w.y;   rC2+=lw*w.z;   rC3+=lw*w.w;
      w = wrl4[m0+3]; lw = l4.w*wwl[m0+3];
      rA0+=l4.w*w.x; rA1+=l4.w*w.y; rA2+=l4.w*w.z; rA3+=l4.w*w.w;
      rC0+=lw*w.x;   rC1+=lw*w.y;   rC2+=lw*w.z;   rC3+=lw*w.w;
    }
    #pragma unroll
    for (int off=8; off>=1; off>>=1){
      rA0 += __shfl_down(rA0, off, 16); rA1 += __shfl_down(rA1, off, 16);
      rA2 += __shfl_down(rA2, off, 16); rA3 += __shfl_down(rA3, off, 16);
      rC0 += __shfl_down(rC0, off, 16); rC1 += __shfl_down(rC1, off, 16);
      rC2 += __shfl_down(rC2, off, 16); rC3 += __shfl_down(rC3, off, 16);
    }
    if (li == 0){
      size_t o2 = ((size_t)b*Nn + n)*Rr;
      rowA[o2+0]=rA0; rowA[o2+1]=rA1; rowA[o2+2]=rA2; rowA[o2+3]=rA3;
      rowC[o2+0]=rC0; rowC[o2+1]=rC1; rowC[o2+2]=rC2; rowC[o2+3]=rC3;
    }
  }
}

// ---------------- K4: fwd/bwd, read content addressing, wr ----------------
__global__ __launch_bounds__(256) void k_readw(
  const float* __restrict__ M, const float* __restrict__ ww_ws,
  const float* __restrict__ er_ws, const float* __restrict__ wv_ws,
  const float* __restrict__ rk_ws, const float* __restrict__ krn_ws,
  const float* __restrict__ rstr_ws, const float* __restrict__ rm_ws,
  const float* __restrict__ P_ws, const float* __restrict__ Q_ws,
  const float* __restrict__ rowA, const float* __restrict__ rowC,
  const float* __restrict__ colA, const float* __restrict__ colC,
  const float* __restrict__ diag, const float* __restrict__ wrp,
  const float* __restrict__ prec, float* __restrict__ wr_out)
{
  const int b = blockIdx.x, t = threadIdx.x;
  __shared__ float rkl[Ww*Rr];
  __shared__ float erl[Ww], wvl[Ww];
  __shared__ float red[Nn];
  rkl[t] = rk_ws[b*Ww*Rr + t];
  if (t < Ww){ erl[t] = er_ws[b*Ww+t]; wvl[t] = wv_ws[b*Ww+t]; }
  __syncthreads();
  const float ww = ww_ws[b*Nn+t];
  const float pr = prec[b*Nn+t];
  const float dg = diag[b*Nn+t];
  float4 wr4 = *reinterpret_cast<const float4*>(wrp + ((size_t)b*Nn+t)*Rr);
  const float Lnn = (1.0f - 2.0f*ww)*dg + ww*pr;
  float4 rA = *reinterpret_cast<const float4*>(rowA + ((size_t)b*Nn+t)*Rr);
  float4 rC = *reinterpret_cast<const float4*>(rowC + ((size_t)b*Nn+t)*Rr);
  float4 cA = *reinterpret_cast<const float4*>(colA + ((size_t)b*Nn+t)*Rr);
  float4 cC = *reinterpret_cast<const float4*>(colC + ((size_t)b*Nn+t)*Rr);
  float4 Pv = *reinterpret_cast<const float4*>(P_ws + b*Rr);
  float4 Qv = *reinterpret_cast<const float4*>(Q_ws + b*Rr);
  float fwdv[4], bwdv[4];
  fwdv[0] = (1.0f-ww)*rA.x - rC.x + ww*Pv.x - Lnn*wr4.x;
  fwdv[1] = (1.0f-ww)*rA.y - rC.y + ww*Pv.y - Lnn*wr4.y;
  fwdv[2] = (1.0f-ww)*rA.z - rC.z + ww*Pv.z - Lnn*wr4.z;
  fwdv[3] = (1.0f-ww)*rA.w - rC.w + ww*Pv.w - Lnn*wr4.w;
  bwdv[0] = (1.0f-ww)*cA.x - cC.x + pr*Qv.x - Lnn*wr4.x;
  bwdv[1] = (1.0f-ww)*cA.y - cC.y + pr*Qv.y - Lnn*wr4.y;
  bwdv[2] = (1.0f-ww)*cA.z - cC.z + pr*Qv.z - Lnn*wr4.z;
  bwdv[3] = (1.0f-ww)*cA.w - cC.w + pr*Qv.w - Lnn*wr4.w;
  // M_new row n=t, sims with read keys
  const float* Mrow = M + ((size_t)b*Nn + t)*Ww;
  float s0=0,s1=0,s2=0,s3=0, nrm=0;
  #pragma unroll 4
  for (int w=0;w<Ww;w+=4){
    float4 m4 = *reinterpret_cast<const float4*>(Mrow + w);
    float mvs[4] = {m4.x, m4.y, m4.z, m4.w};
    #pragma unroll
    for (int i=0;i<4;++i){
      int w_ = w+i;
      float mn = mvs[i]*(1.0f - ww*erl[w_]) + ww*wvl[w_];
      nrm += mn*mn;
      float4 k4 = *reinterpret_cast<const float4*>(&rkl[w_*4]);
      s0 += mn*k4.x; s1 += mn*k4.y; s2 += mn*k4.z; s3 += mn*k4.w;
    }
  }
  float mnorm = sqrtf(nrm);
  float4 kn = *reinterpret_cast<const float4*>(krn_ws + b*Rr);
  float4 rs = *reinterpret_cast<const float4*>(rstr_ws + b*Rr);
  float aa[4];
  aa[0] = rs.x*(s0/(mnorm*kn.x + 1e-6f));
  aa[1] = rs.y*(s1/(mnorm*kn.y + 1e-6f));
  aa[2] = rs.z*(s2/(mnorm*kn.z + 1e-6f));
  aa[3] = rs.w*(s3/(mnorm*kn.w + 1e-6f));
  float cr[4];
  #pragma unroll
  for (int r=0;r<4;++r){
    red[t]=aa[r]; __syncthreads();
    for (int st=128; st>0; st>>=1){ if (t<st) red[t]=fmaxf(red[t],red[t+st]); __syncthreads(); }
    float mx = red[0]; __syncthreads();
    float e = expf(aa[r]-mx);
    red[t]=e; __syncthreads();
    for (int st=128; st>0; st>>=1){ if (t<st) red[t]+=red[t+st]; __syncthreads(); }
    cr[r] = e/red[0]; __syncthreads();
  }
  float wro[4];
  #pragma unroll
  for (int r=0;r<4;++r){
    float m0 = rm_ws[b*12 + r];
    float m1 = rm_ws[b*12 + 4 + r];
    float m2 = rm_ws[b*12 + 8 + r];
    wro[r] = m0*bwdv[r] + m1*cr[r] + m2*fwdv[r];
  }
  float4 o4; o4.x=wro[0]; o4.y=wro[1]; o4.z=wro[2]; o4.w=wro[3];
  *reinterpret_cast<float4*>(wr_out + ((size_t)b*Nn+t)*Rr) = o4;
}

// ---------------- K5: read vectors + final output --------------------------
__global__ __launch_bounds__(256) void k_out(
  const float* __restrict__ M, const float* __restrict__ h_ws,
  const float* __restrict__ ww_ws, const float* __restrict__ er_ws,
  const float* __restrict__ wv_ws, const float* __restrict__ wr_ws,
  const float* __restrict__ Wo, const float* __restrict__ bo,
  float* __restrict__ out)
{
  const int b = blockIdx.x, t = threadIdx.x;
  __shared__ float hl[Uu];
  __shared__ float wwl[Nn];
  __shared__ float wrl[Nn][4];
  __shared__ float erl[Ww], wvl[Ww];
  __shared__ float rvl[Ww*Rr];
  __shared__ float part[2][OUTsz];
  hl[t]  = h_ws[b*Uu+t];
  wwl[t] = ww_ws[b*Nn+t];
  {
    float4 w4 = *reinterpret_cast<const float4*>(wr_ws + ((size_t)b*Nn+t)*Rr);
    wrl[t][0]=w4.x; wrl[t][1]=w4.y; wrl[t][2]=w4.z; wrl[t][3]=w4.w;
  }
  if (t < Ww){ erl[t]=er_ws[b*Ww+t]; wvl[t]=wv_ws[b*Ww+t]; }
  __syncthreads();
  const int w = t & 63, r = t >> 6;
  const float er_w = erl[w], wv_w = wvl[w];
  float acc = 0.0f;
  #pragma unroll 4
  for (int n=0;n<Nn;++n){
    float m = M[((size_t)b*Nn + n)*Ww + w];
    float wwn = wwl[n];
    float mn = m*(1.0f - wwn*er_w) + wwn*wv_w;
    acc += mn*wrl[n][r];
  }
  rvl[w*Rr + r] = acc;
  __syncthreads();
  const int j = t & 127, half = t >> 7;
  float o = 0.0f;
  #pragma unroll 4
  for (int k = half*256; k < half*256 + 256; ++k){
    float src = (k < Uu) ? hl[k] : rvl[k - Uu];
    o += src*Wo[(size_t)k*OUTsz + j];
  }
  part[half][j] = o;
  __syncthreads();
  if (t < OUTsz){
    float res = part[0][t] + part[1][t] + bo[t];
    res = fminf(fmaxf(res, -20.0f), 20.0f);
    out[b*OUTsz + t] = res;
  }
}

extern "C" void kernel_launch(void* const* d_in, const int* in_sizes, int n_in,
                              void* d_out, int out_size, void* d_ws, size_t ws_size,
                              hipStream_t stream)
{
  const float* inputs = (const float*)d_in[0];
  const float* M      = (const float*)d_in[1];
  const float* usage  = (const float*)d_in[2];
  const float* link   = (const float*)d_in[3];
  const float* prec   = (const float*)d_in[4];
  const float* wwp    = (const float*)d_in[5];
  const float* wrp    = (const float*)d_in[6];
  const float* hp     = (const float*)d_in[7];
  const float* cp     = (const float*)d_in[8];
  const float* rvp    = (const float*)d_in[9];
  const float* Wk     = (const float*)d_in[10];
  const float* Wr     = (const float*)d_in[11];
  const float* bl     = (const float*)d_in[12];
  const float* Wi     = (const float*)d_in[13];
  const float* bi     = (const float*)d_in[14];
  const float* Wo     = (const float*)d_in[15];
  const float* bo     = (const float*)d_in[16];

  float* ws = (float*)d_ws;
  float* h_ws    = ws;
  float* ww_ws   = h_ws   + Bsz*Uu;
  float* er_ws   = ww_ws  + Bsz*Nn;
  float* wv_ws   = er_ws  + Bsz*Ww;
  float* rk_ws   = wv_ws  + Bsz*Ww;
  float* krn_ws  = rk_ws  + Bsz*Ww*Rr;
  float* rstr_ws = krn_ws + Bsz*Rr;
  float* rm_ws   = rstr_ws+ Bsz*Rr;
  float* P_ws    = rm_ws  + Bsz*3*Rr;
  float* Q_ws    = P_ws   + Bsz*Rr;
  float* rowA    = Q_ws   + Bsz*Rr;
  float* rowC    = rowA   + (size_t)Bsz*Nn*Rr;
  float* colA    = rowC   + (size_t)Bsz*Nn*Rr;
  float* colC    = colA   + (size_t)Bsz*Nn*Rr;
  float* diag    = colC   + (size_t)Bsz*Nn*Rr;
  float* wr_ws   = diag   + Bsz*Nn;

  k_lstm<<<dim3(Bsz/4), dim3(256), 0, stream>>>(inputs, rvp, hp, cp, Wk, Wr, bl, h_ws);
  k_iface<<<dim3(Bsz), dim3(256), 0, stream>>>(h_ws, Wi, bi, usage, wwp, wrp, prec, M,
      ww_ws, er_ws, wv_ws, rk_ws, krn_ws, rstr_ws, rm_ws, P_ws, Q_ws);
  k_link<<<dim3(Bsz), dim3(256), 0, stream>>>(link, wrp, ww_ws, rowA, rowC, colA, colC, diag);
  k_readw<<<dim3(Bsz), dim3(256), 0, stream>>>(M, ww_ws, er_ws, wv_ws, rk_ws, krn_ws,
      rstr_ws, rm_ws, P_ws, Q_ws, rowA, rowC, colA, colC, diag, wrp, prec, wr_ws);
  k_out<<<dim3(Bsz), dim3(256), 0, stream>>>(M, h_ws, ww_ws, er_ws, wv_ws, wr_ws,
      Wo, bo, (float*)d_out);
}